// Round 6
// baseline (387.503 us; speedup 1.0000x reference)
//
#include <hip/hip_runtime.h>
#include <hip/hip_cooperative_groups.h>

namespace cg = cooperative_groups;

// LGNLayer. Preferred path: ONE cooperative kernel (3 phases, 2 grid.sync()).
// Fallback path (if cooperative launch unavailable/rejected): 3 kernels (proven R3).
// Outputs concatenated: new_firing[8192], lgn_act[2048], lgn_weights[2048*8192], lgn_threshold[2048].

constexpr int N_RET = 8192;
constexpr int N_LGN = 2048;
constexpr float ETA = 0.1f;
constexpr float MU_WTS = 2.5f;
constexpr int NT = 256;

typedef float vf4 __attribute__((ext_vector_type(4)));

__device__ __forceinline__ vf4 ntload4(const float* p) {
    return __builtin_nontemporal_load(reinterpret_cast<const vf4*>(p));
}
__device__ __forceinline__ void ntstore4(float* p, vf4 v) {
    __builtin_nontemporal_store(v, reinterpret_cast<vf4*>(p));
}
__device__ __forceinline__ vf4 ld4(const float* p) {
    return *reinterpret_cast<const vf4*>(p);
}
__device__ __forceinline__ void st4(float* p, vf4 v) {
    *reinterpret_cast<vf4*>(p) = v;
}

// ================= fused cooperative kernel =================
__global__ __launch_bounds__(NT, 4) void k_fused(
    const float* __restrict__ rw, const float* __restrict__ rthr,
    const float* __restrict__ lw, const float* __restrict__ lthr,
    const float* __restrict__ fir,
    float* __restrict__ o_fir, float* __restrict__ o_act,
    float* __restrict__ o_w, float* __restrict__ o_thr)
{
    cg::grid_group grid = cg::this_grid();
    const int nblk = gridDim.x;
    const int bid = blockIdx.x;
    const int t = threadIdx.x;
    const int lane = t & 63, wv = t >> 6;
    __shared__ float s[4];

    // ---------- phase 1: retina matvec -> new_firing ----------
    for (int row = bid; row < N_RET; row += nblk) {
        const float* __restrict__ wr = rw + (size_t)row * N_RET;
        vf4 acc = (vf4)(0.0f);
#pragma unroll
        for (int k = 0; k < (N_RET / 4) / NT; ++k) {   // 8 iterations
            const int j = (t + k * NT) * 4;
            acc += ntload4(wr + j) * ld4(fir + j);
        }
        float v = (acc.x + acc.y) + (acc.z + acc.w);
#pragma unroll
        for (int off = 32; off > 0; off >>= 1) v += __shfl_down(v, off, 64);
        if (lane == 0) s[wv] = v;
        __syncthreads();
        if (t == 0) {
            const float x = (s[0] + s[1]) + (s[2] + s[3]);
            o_fir[row] = (x > rthr[row]) ? 1.0f : 0.0f;
        }
        __syncthreads();
    }
    __threadfence();   // release new_firing device-wide (cross-XCD)
    grid.sync();

    // ---------- phase 2: lgn matvec + relu + fused weights copy ----------
    for (int row = bid; row < N_LGN; row += nblk) {
        const float* __restrict__ wr = lw + (size_t)row * N_RET;
        float* __restrict__ wo = o_w + (size_t)row * N_RET;
        vf4 acc = (vf4)(0.0f);
#pragma unroll
        for (int k = 0; k < (N_RET / 4) / NT; ++k) {   // 8 iterations
            const int j = (t + k * NT) * 4;
            const vf4 w = ntload4(wr + j);
            const vf4 f = ld4(o_fir + j);
            ntstore4(wo + j, w);
            acc += w * f;
        }
        float v = (acc.x + acc.y) + (acc.z + acc.w);
#pragma unroll
        for (int off = 32; off > 0; off >>= 1) v += __shfl_down(v, off, 64);
        if (lane == 0) s[wv] = v;
        __syncthreads();
        if (t == 0) o_act[row] = fmaxf((s[0] + s[1]) + (s[2] + s[3]), 0.0f);
        __syncthreads();
    }
    __threadfence();
    grid.sync();

    // ---------- phase 3: block 0 only ----------
    if (bid != 0) return;
    __shared__ float sv[4];
    __shared__ int si[4];
    __shared__ float s_val, s_mean;
    __shared__ int s_idx;

    float bv = -1.0f;
    int bi = 0x40000000;
#pragma unroll
    for (int k = 0; k < N_LGN / NT; ++k) {   // ascending j: strict > keeps first index
        const int j = t + k * NT;
        const float a = fmaxf(o_act[j] - lthr[j], 0.0f);
        if (a > bv) { bv = a; bi = j; }
    }
#pragma unroll
    for (int off = 32; off > 0; off >>= 1) {
        const float ov = __shfl_down(bv, off, 64);
        const int oi = __shfl_down(bi, off, 64);
        if (ov > bv || (ov == bv && oi < bi)) { bv = ov; bi = oi; }
    }
    if (lane == 0) { sv[wv] = bv; si[wv] = bi; }
    __syncthreads();
    if (t == 0) {
        float v = sv[0]; int i = si[0];
#pragma unroll
        for (int k = 1; k < 4; ++k)
            if (sv[k] > v || (sv[k] == v && si[k] < i)) { v = sv[k]; i = si[k]; }
        s_val = v; s_idx = i;
    }
    __syncthreads();
    const float val = s_val;
    const int idx = s_idx;

#pragma unroll
    for (int k = 0; k < N_LGN / NT; ++k) {
        const int j = t + k * NT;
        float tv = lthr[j];
        if (val > 0.0f && j == idx) tv += 0.005f * val;
        o_thr[j] = tv;
    }
    if (!(val > 0.0f)) return;

    const float* __restrict__ wr = lw + (size_t)idx * N_RET;
    float* __restrict__ wo = o_w + (size_t)idx * N_RET;
    const float av = 0.5f * (ETA * val);

    vf4 x[(N_RET / 4) / NT];
    float part = 0.0f;
#pragma unroll
    for (int k = 0; k < (N_RET / 4) / NT; ++k) {
        const int j = (t + k * NT) * 4;
        const vf4 w = ld4(wr + j);
        const vf4 f = ld4(o_fir + j);
        vf4 v = (w + av * f) + av * f;
        x[k] = v;
        part += (v.x + v.y) + (v.z + v.w);
    }
#pragma unroll
    for (int off = 32; off > 0; off >>= 1) part += __shfl_down(part, off, 64);
    if (lane == 0) sv[wv] = part;
    __syncthreads();
    if (t == 0) s_mean = ((sv[0] + sv[1]) + (sv[2] + sv[3])) / (float)N_RET;
    __syncthreads();
    const float m = s_mean;
#pragma unroll
    for (int k = 0; k < (N_RET / 4) / NT; ++k) {
        const int j = (t + k * NT) * 4;
        st4(wo + j, x[k] / m * MU_WTS);
    }
}

// ================= fallback kernels (proven R3 path) =================
__global__ __launch_bounds__(256) void k_retina(
    const float* __restrict__ rw, const float* __restrict__ rthr,
    const float* __restrict__ firing, float* __restrict__ new_firing)
{
    const int row = blockIdx.x;
    const int t = threadIdx.x;
    const float* __restrict__ wr = rw + (size_t)row * N_RET;
    vf4 acc = (vf4)(0.0f);
#pragma unroll
    for (int k = 0; k < (N_RET / 4) / 256; ++k) {
        const int j = (t + k * 256) * 4;
        acc += ntload4(wr + j) * ld4(firing + j);
    }
    float v = (acc.x + acc.y) + (acc.z + acc.w);
#pragma unroll
    for (int off = 32; off > 0; off >>= 1) v += __shfl_down(v, off, 64);
    __shared__ float s[4];
    const int lane = t & 63, wv = t >> 6;
    if (lane == 0) s[wv] = v;
    __syncthreads();
    if (t == 0) {
        const float x = (s[0] + s[1]) + (s[2] + s[3]);
        new_firing[row] = (x > rthr[row]) ? 1.0f : 0.0f;
    }
}

__global__ __launch_bounds__(256) void k_lgn(
    const float* __restrict__ lw, const float* __restrict__ firing,
    float* __restrict__ lgn_act, float* __restrict__ w_out)
{
    const int row = blockIdx.x;
    const int t = threadIdx.x;
    const float* __restrict__ wr = lw + (size_t)row * N_RET;
    float* __restrict__ wo = w_out + (size_t)row * N_RET;
    vf4 acc = (vf4)(0.0f);
#pragma unroll
    for (int k = 0; k < (N_RET / 4) / 256; ++k) {
        const int j = (t + k * 256) * 4;
        const vf4 w = ntload4(wr + j);
        const vf4 f = ld4(firing + j);
        ntstore4(wo + j, w);
        acc += w * f;
    }
    float v = (acc.x + acc.y) + (acc.z + acc.w);
#pragma unroll
    for (int off = 32; off > 0; off >>= 1) v += __shfl_down(v, off, 64);
    __shared__ float s[4];
    const int lane = t & 63, wv = t >> 6;
    if (lane == 0) s[wv] = v;
    __syncthreads();
    if (t == 0) {
        const float x = (s[0] + s[1]) + (s[2] + s[3]);
        lgn_act[row] = fmaxf(x, 0.0f);
    }
}

__global__ __launch_bounds__(1024) void k_wta(
    const float* __restrict__ lgn_act, const float* __restrict__ lthr,
    const float* __restrict__ lw, const float* __restrict__ firing,
    float* __restrict__ thr_out, float* __restrict__ w_out)
{
    const int t = threadIdx.x;
    const int lane = t & 63, wv = t >> 6;
    __shared__ float sv[16];
    __shared__ int si[16];
    __shared__ float s_val, s_mean;
    __shared__ int s_idx;

    float bv = -1.0f;
    int bi = 0x40000000;
#pragma unroll
    for (int k = 0; k < N_LGN / 1024; ++k) {
        const int j = t + k * 1024;
        const float a = fmaxf(lgn_act[j] - lthr[j], 0.0f);
        if (a > bv) { bv = a; bi = j; }
    }
#pragma unroll
    for (int off = 32; off > 0; off >>= 1) {
        const float ov = __shfl_down(bv, off, 64);
        const int oi = __shfl_down(bi, off, 64);
        if (ov > bv || (ov == bv && oi < bi)) { bv = ov; bi = oi; }
    }
    if (lane == 0) { sv[wv] = bv; si[wv] = bi; }
    __syncthreads();
    if (t == 0) {
        float v = sv[0]; int i = si[0];
#pragma unroll
        for (int k = 1; k < 16; ++k)
            if (sv[k] > v || (sv[k] == v && si[k] < i)) { v = sv[k]; i = si[k]; }
        s_val = v; s_idx = i;
    }
    __syncthreads();
    const float val = s_val;
    const int idx = s_idx;

#pragma unroll
    for (int k = 0; k < N_LGN / 1024; ++k) {
        const int j = t + k * 1024;
        float tv = lthr[j];
        if (val > 0.0f && j == idx) tv += 0.005f * val;
        thr_out[j] = tv;
    }
    if (!(val > 0.0f)) return;

    const float* __restrict__ wr = lw + (size_t)idx * N_RET;
    float* __restrict__ wo = w_out + (size_t)idx * N_RET;
    const float av = 0.5f * (ETA * val);

    vf4 x[2];
    float part = 0.0f;
#pragma unroll
    for (int k = 0; k < (N_RET / 4) / 1024; ++k) {
        const int j = (t + k * 1024) * 4;
        const vf4 w = ld4(wr + j);
        const vf4 f = ld4(firing + j);
        vf4 v = (w + av * f) + av * f;
        x[k] = v;
        part += (v.x + v.y) + (v.z + v.w);
    }
#pragma unroll
    for (int off = 32; off > 0; off >>= 1) part += __shfl_down(part, off, 64);
    __shared__ float red[16];
    if (lane == 0) red[wv] = part;
    __syncthreads();
    if (t == 0) {
        float sum = 0.0f;
#pragma unroll
        for (int k = 0; k < 16; ++k) sum += red[k];
        s_mean = sum / (float)N_RET;
    }
    __syncthreads();
    const float m = s_mean;
#pragma unroll
    for (int k = 0; k < (N_RET / 4) / 1024; ++k) {
        const int j = (t + k * 1024) * 4;
        st4(wo + j, x[k] / m * MU_WTS);
    }
}

extern "C" void kernel_launch(void* const* d_in, const int* in_sizes, int n_in,
                              void* d_out, int out_size, void* d_ws, size_t ws_size,
                              hipStream_t stream)
{
    const float* rw   = (const float*)d_in[0];
    const float* rthr = (const float*)d_in[1];
    const float* lw   = (const float*)d_in[2];
    const float* lthr = (const float*)d_in[3];
    const float* fir  = (const float*)d_in[4];

    float* out   = (float*)d_out;
    float* o_fir = out;                                         // [8192]
    float* o_act = out + N_RET;                                 // [2048]
    float* o_w   = out + N_RET + N_LGN;                         // [2048*8192]
    float* o_thr = o_w + (size_t)N_LGN * N_RET;                 // [2048]

    // ---- try cooperative fused path (deterministic: same device, same result) ----
    bool coop_done = false;
    int occ = 0;
    hipError_t oe = hipOccupancyMaxActiveBlocksPerMultiprocessor(&occ, k_fused, NT, 0);
    if (oe == hipSuccess && occ > 0) {
        int nblk = occ * 256;            // 256 CUs on MI355X
        if (nblk > 1024) nblk = 1024;    // enough parallelism for BW; grid-stride handles any nblk
        void* args[] = { (void*)&rw, (void*)&rthr, (void*)&lw, (void*)&lthr, (void*)&fir,
                         (void*)&o_fir, (void*)&o_act, (void*)&o_w, (void*)&o_thr };
        hipError_t le = hipLaunchCooperativeKernel(k_fused, dim3(nblk), dim3(NT),
                                                   args, 0, stream);
        if (le == hipSuccess) coop_done = true;
        else (void)hipGetLastError();    // clear sticky error, fall back
    } else {
        (void)hipGetLastError();
    }

    if (!coop_done) {
        hipLaunchKernelGGL(k_retina, dim3(N_RET), dim3(256),  0, stream, rw, rthr, fir, o_fir);
        hipLaunchKernelGGL(k_lgn,    dim3(N_LGN), dim3(256),  0, stream, lw, o_fir, o_act, o_w);
        hipLaunchKernelGGL(k_wta,    dim3(1),     dim3(1024), 0, stream, o_act, lthr, lw, o_fir, o_thr, o_w);
    }
}

// Round 7
// 75.118 us; speedup vs baseline: 5.1586x; 5.1586x over previous
//
#include <hip/hip_runtime.h>

// LGNLayer: 3-kernel structure (proven R3) with wave-per-row matvecs.
//   k_retina: 256MB stream matvec, 1 wave = 1 row, no block barriers.
//   k_lgn:    64MB read + 64MB copy-out fused, 1 wave = 1 row.
//   k_wta:    argmax + threshold + winner-row update (single block, 1024 thr).
// Outputs concatenated: new_firing[8192], lgn_act[2048], lgn_weights[2048*8192], lgn_threshold[2048].

constexpr int N_RET = 8192;
constexpr int N_LGN = 2048;
constexpr float ETA = 0.1f;
constexpr float MU_WTS = 2.5f;

typedef float vf4 __attribute__((ext_vector_type(4)));

__device__ __forceinline__ vf4 ntload4(const float* p) {
    return __builtin_nontemporal_load(reinterpret_cast<const vf4*>(p));
}
__device__ __forceinline__ void ntstore4(float* p, vf4 v) {
    __builtin_nontemporal_store(v, reinterpret_cast<vf4*>(p));
}
__device__ __forceinline__ vf4 ld4(const float* p) {
    return *reinterpret_cast<const vf4*>(p);
}
__device__ __forceinline__ void st4(float* p, vf4 v) {
    *reinterpret_cast<vf4*>(p) = v;
}

// ---------- K1: new_firing = (retina_weights @ is_firing > retina_threshold) ----------
// 1 wave per row; 4 rows per 256-thread block; no __syncthreads, no LDS.
__global__ __launch_bounds__(256) void k_retina(
    const float* __restrict__ rw, const float* __restrict__ rthr,
    const float* __restrict__ firing, float* __restrict__ new_firing)
{
    const int t = threadIdx.x;
    const int lane = t & 63, wv = t >> 6;
    const int row = blockIdx.x * 4 + wv;
    const float* __restrict__ wr = rw + (size_t)row * N_RET;
    vf4 acc = (vf4)(0.0f);
#pragma unroll 8
    for (int it = 0; it < (N_RET / 4) / 64; ++it) {   // 32 iterations, 8-deep pipelined
        const int j = (lane + it * 64) * 4;
        acc += ntload4(wr + j) * ld4(firing + j);      // weights stream; firing L1/L2-hot
    }
    float v = (acc.x + acc.y) + (acc.z + acc.w);
#pragma unroll
    for (int off = 32; off > 0; off >>= 1) v += __shfl_down(v, off, 64);
    if (lane == 0) new_firing[row] = (v > rthr[row]) ? 1.0f : 0.0f;
}

// ---------- K2: lgn_act = relu(lgn_weights @ new_firing); fused weights copy-out ----------
// 1 wave per row; 4 rows per block.
__global__ __launch_bounds__(256) void k_lgn(
    const float* __restrict__ lw, const float* __restrict__ firing,
    float* __restrict__ lgn_act, float* __restrict__ w_out)
{
    const int t = threadIdx.x;
    const int lane = t & 63, wv = t >> 6;
    const int row = blockIdx.x * 4 + wv;
    const float* __restrict__ wr = lw + (size_t)row * N_RET;
    float* __restrict__ wo = w_out + (size_t)row * N_RET;
    vf4 acc = (vf4)(0.0f);
#pragma unroll 8
    for (int it = 0; it < (N_RET / 4) / 64; ++it) {   // 32 iterations
        const int j = (lane + it * 64) * 4;
        const vf4 w = ntload4(wr + j);
        const vf4 f = ld4(firing + j);
        ntstore4(wo + j, w);                           // fused copy, streaming store
        acc += w * f;
    }
    float v = (acc.x + acc.y) + (acc.z + acc.w);
#pragma unroll
    for (int off = 32; off > 0; off >>= 1) v += __shfl_down(v, off, 64);
    if (lane == 0) lgn_act[row] = fmaxf(v, 0.0f);
}

// ---------- K3: argmax + threshold output + winner-row update (single block, 1024 thr) ----------
__global__ __launch_bounds__(1024) void k_wta(
    const float* __restrict__ lgn_act, const float* __restrict__ lthr,
    const float* __restrict__ lw, const float* __restrict__ firing,
    float* __restrict__ thr_out, float* __restrict__ w_out)
{
    const int t = threadIdx.x;
    const int lane = t & 63, wv = t >> 6;
    __shared__ float sv[16];
    __shared__ int si[16];
    __shared__ float s_val, s_mean;
    __shared__ int s_idx;

    // argmax(act) with first-index tie-break (ascending scan, strict >)
    float bv = -1.0f;      // act >= 0 always
    int bi = 0x40000000;
#pragma unroll
    for (int k = 0; k < N_LGN / 1024; ++k) {   // 2 iterations, ascending j per thread
        const int j = t + k * 1024;
        const float a = fmaxf(lgn_act[j] - lthr[j], 0.0f);
        if (a > bv) { bv = a; bi = j; }
    }
#pragma unroll
    for (int off = 32; off > 0; off >>= 1) {
        const float ov = __shfl_down(bv, off, 64);
        const int oi = __shfl_down(bi, off, 64);
        if (ov > bv || (ov == bv && oi < bi)) { bv = ov; bi = oi; }
    }
    if (lane == 0) { sv[wv] = bv; si[wv] = bi; }
    __syncthreads();
    if (t == 0) {
        float v = sv[0]; int i = si[0];
#pragma unroll
        for (int k = 1; k < 16; ++k)
            if (sv[k] > v || (sv[k] == v && si[k] < i)) { v = sv[k]; i = si[k]; }
        s_val = v; s_idx = i;
    }
    __syncthreads();
    const float val = s_val;
    const int idx = s_idx;

    // threshold output (winner patched inline)
#pragma unroll
    for (int k = 0; k < N_LGN / 1024; ++k) {
        const int j = t + k * 1024;
        float tv = lthr[j];
        if (val > 0.0f && j == idx) tv += 0.005f * val;
        thr_out[j] = tv;
    }
    if (!(val > 0.0f)) return;   // uniform: no weight update

    // winner row: x = (w + a) + a; row = x / mean(x) * MU_WTS
    const float* __restrict__ wr = lw + (size_t)idx * N_RET;
    float* __restrict__ wo = w_out + (size_t)idx * N_RET;
    const float av = 0.5f * (ETA * val);   // a = av * f, f in {0,1}

    vf4 x[2];
    float part = 0.0f;
#pragma unroll
    for (int k = 0; k < (N_RET / 4) / 1024; ++k) {   // 2 iterations
        const int j = (t + k * 1024) * 4;
        const vf4 w = ld4(wr + j);
        const vf4 f = ld4(firing + j);
        vf4 v = (w + av * f) + av * f;               // two half-additions, like ref
        x[k] = v;
        part += (v.x + v.y) + (v.z + v.w);
    }
#pragma unroll
    for (int off = 32; off > 0; off >>= 1) part += __shfl_down(part, off, 64);
    __shared__ float red[16];
    if (lane == 0) red[wv] = part;
    __syncthreads();
    if (t == 0) {
        float sum = 0.0f;
#pragma unroll
        for (int k = 0; k < 16; ++k) sum += red[k];
        s_mean = sum / (float)N_RET;
    }
    __syncthreads();
    const float m = s_mean;
#pragma unroll
    for (int k = 0; k < (N_RET / 4) / 1024; ++k) {
        const int j = (t + k * 1024) * 4;
        st4(wo + j, x[k] / m * MU_WTS);
    }
}

extern "C" void kernel_launch(void* const* d_in, const int* in_sizes, int n_in,
                              void* d_out, int out_size, void* d_ws, size_t ws_size,
                              hipStream_t stream)
{
    const float* rw   = (const float*)d_in[0];   // retina_weights [8192, 8192]
    const float* rthr = (const float*)d_in[1];   // retina_threshold [8192]
    const float* lw   = (const float*)d_in[2];   // lgn_weights [2048, 8192]
    const float* lthr = (const float*)d_in[3];   // lgn_threshold [2048]
    const float* fir  = (const float*)d_in[4];   // is_firing [8192]

    float* out   = (float*)d_out;
    float* o_fir = out;                                         // [8192]
    float* o_act = out + N_RET;                                 // [2048]
    float* o_w   = out + N_RET + N_LGN;                         // [2048*8192]
    float* o_thr = o_w + (size_t)N_LGN * N_RET;                 // [2048]

    hipLaunchKernelGGL(k_retina, dim3(N_RET / 4), dim3(256),  0, stream, rw, rthr, fir, o_fir);
    hipLaunchKernelGGL(k_lgn,    dim3(N_LGN / 4), dim3(256),  0, stream, lw, o_fir, o_act, o_w);
    hipLaunchKernelGGL(k_wta,    dim3(1),         dim3(1024), 0, stream, o_act, lthr, lw, o_fir, o_thr, o_w);
}